// Round 3
// baseline (1692.091 us; speedup 1.0000x reference)
//
#include <hip/hip_runtime.h>
#include <hip/hip_bf16.h>

typedef __hip_bfloat16 bf16;
typedef __bf16 bf16x8 __attribute__((ext_vector_type(8)));
typedef float f32x4 __attribute__((ext_vector_type(4)));

// total tokens: 32 images * 56*56 = 100352; 2048 windows of 49 tokens
constexpr int TOK_ALL = 100352;

// bitmask: bit i set iff (i % 7) < 4   (used for window-region tests, i < 64)
constexpr unsigned long long build_mod7lt4() {
  unsigned long long m = 0;
  for (int i = 0; i < 64; ++i) if (i % 7 < 4) m |= (1ull << i);
  return m;
}
constexpr unsigned long long R74 = build_mod7lt4();

// global window-token row -> (b,h,w) flat index (window reverse + roll(+3,+3))
__device__ __forceinline__ long dst_index(int grow) {
  int w  = grow / 49;
  int n  = grow - w * 49;
  int b  = w >> 6;
  int wi = w & 63;
  int wh = wi >> 3, ww = wi & 7;
  int r  = n / 7,  cl = n - (n / 7) * 7;
  int hh = wh * 7 + r + 3;  if (hh >= 56) hh -= 56;
  int vv = ww * 7 + cl + 3; if (vv >= 56) vv -= 56;
  return ((long)b * 3136 + hh * 56 + vv);
}

// ---------------------------------------------------------------------------
// TN GEMM, skinny-K form: C[M,N] = A[M,K] * Bt[N,K]^T, fused epilogues.
// Block = 256 M-rows x 64 N-cols, 4 waves stacked along M (each 64x64).
// B panel (64 x KC=384, padded stride 784B -> 2-way-conflict ds_reads) is
// staged ONCE per K-chunk; A fragments are loaded straight from global into
// VGPRs. The 12-kslice MFMA loop has NO barriers / NO vmcnt(0) drains.
// EPI: 0 = +bias -> bf16, 1 = +bias + scatter + f32 resid -> f32,
//      2 = +bias + tanh-GELU -> bf16, 3 = +bias + f32 resid -> f32 (in-place ok)
template <int EPI>
__global__ __launch_bounds__(256) void gemm_bt(
    const bf16* __restrict__ A, const bf16* __restrict__ Bt,
    const float* __restrict__ bias, void* __restrict__ Cout_,
    const float* __restrict__ resid, int M, int N, int K, int rowoff) {
  constexpr int KC = 384;                       // K-chunk (K % 384 == 0 here)
  __shared__ __align__(16) char Bs[64 * 784];   // 64 rows x 768B + 16B pad

  const int tid  = threadIdx.x;
  const int wv   = tid >> 6;
  const int lane = tid & 63;
  const int quad = lane >> 4;
  const int c    = lane & 15;
  const int n0   = blockIdx.x * 64;
  const int m0   = blockIdx.y * 256;
  const size_t rowb = (size_t)K * 2;

  const char* Ab = (const char*)A;
  const char* Bb = (const char*)Bt + (size_t)n0 * rowb;

  f32x4 acc[4][4];
#pragma unroll
  for (int i = 0; i < 4; ++i)
#pragma unroll
    for (int j = 0; j < 4; ++j) acc[i][j] = (f32x4){0.f, 0.f, 0.f, 0.f};

  const int rA = wv * 64 + c;   // lane's base row within the 256-row tile

  for (int kc0 = 0; kc0 < K; kc0 += KC) {
    if (kc0) __syncthreads();
    // stage B panel: 3072 x 16B chunks, 12 per thread (row-padded LDS)
#pragma unroll
    for (int i = 0; i < 12; ++i) {
      int cid = i * 256 + tid;
      int row = cid / 48, j = cid - row * 48;
      *(uint4*)(Bs + row * 784 + j * 16) =
          *(const uint4*)(Bb + (size_t)row * rowb + kc0 * 2 + j * 16);
    }
    __syncthreads();

#pragma unroll 2
    for (int ks = 0; ks < 12; ++ks) {
      bf16x8 af[4], bfr[4];
      const size_t kbyte = (size_t)(kc0 + ks * 32) * 2 + quad * 16;
#pragma unroll
      for (int mt = 0; mt < 4; ++mt) {
        int row = m0 + rA + mt * 16;
        row = row < M ? row : M - 1;           // fallback-path clamp
        af[mt] = *(const bf16x8*)(Ab + (size_t)row * rowb + kbyte);
      }
#pragma unroll
      for (int nt = 0; nt < 4; ++nt)
        bfr[nt] = *(const bf16x8*)(Bs + (nt * 16 + c) * 784 + ks * 64 + quad * 16);
#pragma unroll
      for (int mt = 0; mt < 4; ++mt)
#pragma unroll
        for (int nt = 0; nt < 4; ++nt)
          acc[mt][nt] = __builtin_amdgcn_mfma_f32_16x16x32_bf16(af[mt], bfr[nt], acc[mt][nt], 0, 0, 0);
    }
  }

  // epilogue  (C/D layout: col = lane&15, row = quad*4 + reg)
  bf16*  CoutB = (bf16*)Cout_;
  float* CoutF = (float*)Cout_;
  float bcol[4];
#pragma unroll
  for (int nt = 0; nt < 4; ++nt)
    bcol[nt] = bias[n0 + nt * 16 + c];

#pragma unroll
  for (int mt = 0; mt < 4; ++mt) {
#pragma unroll
    for (int r = 0; r < 4; ++r) {
      int grow = m0 + wv * 64 + mt * 16 + quad * 4 + r;
      if (grow >= M) continue;
      long dst_row = 0;
      if constexpr (EPI == 1) dst_row = dst_index(rowoff + grow);
#pragma unroll
      for (int nt = 0; nt < 4; ++nt) {
        int col = n0 + nt * 16 + c;
        float v = acc[mt][nt][r] + bcol[nt];
        if constexpr (EPI == 0) {
          CoutB[(size_t)grow * N + col] = __float2bfloat16(v);
        } else if constexpr (EPI == 1) {
          size_t dst = (size_t)dst_row * 384 + col;
          CoutF[dst] = v + resid[dst];
        } else if constexpr (EPI == 2) {
          float u = 0.7978845608f * (v + 0.044715f * v * v * v);
          float t = __expf(2.f * u);
          float g = v * (1.f - 1.f / (t + 1.f));   // 0.5*v*(1+tanh(u))
          CoutB[(size_t)grow * N + col] = __float2bfloat16(g);
        } else {
          size_t dst = (size_t)grow * N + col;
          CoutF[dst] = v + resid[dst];
        }
      }
    }
  }
}

// ---------------------------------------------------------------------------
// LayerNorm, one wave per token; f32 in -> bf16 out.
// gather=1: LN1 + roll(-3,-3) + window partition (rows in window order)
__global__ __launch_bounds__(256) void ln_kernel(
    const float* __restrict__ x, const float* __restrict__ sc,
    const float* __restrict__ bi, bf16* __restrict__ y, int gather, int goff) {
  int tok  = blockIdx.x * 4 + (threadIdx.x >> 6);
  int lane = threadIdx.x & 63;
  size_t src;
  if (gather) {
    int tg = goff + tok;
    int w  = tg / 49, n = tg - (tg / 49) * 49;
    int b  = w >> 6, wi = w & 63;
    int wh = wi >> 3, ww = wi & 7;
    int r  = n / 7, cl = n - (n / 7) * 7;
    int hh = wh * 7 + r + 3;  if (hh >= 56) hh -= 56;
    int vv = ww * 7 + cl + 3; if (vv >= 56) vv -= 56;
    src = ((size_t)b * 3136 + hh * 56 + vv) * 384;
  } else {
    src = (size_t)tok * 384;
  }
  float v[6], s = 0.f, sq = 0.f;
#pragma unroll
  for (int j = 0; j < 6; ++j) {
    v[j] = x[src + lane + j * 64];
    s += v[j]; sq += v[j] * v[j];
  }
#pragma unroll
  for (int m = 32; m; m >>= 1) { s += __shfl_xor(s, m); sq += __shfl_xor(sq, m); }
  float mu  = s * (1.f / 384.f);
  float var = sq * (1.f / 384.f) - mu * mu;
  float rs  = rsqrtf(var + 1e-6f);
#pragma unroll
  for (int j = 0; j < 6; ++j) {
    int c = lane + j * 64;
    y[(size_t)tok * 384 + c] = __float2bfloat16((v[j] - mu) * rs * sc[c] + bi[c]);
  }
}

// ---------------------------------------------------------------------------
// MFMA attention: one wave (64-thread block) per (window, head). N=49, Dh=32.
__global__ __launch_bounds__(64) void attn_mfma(
    const __bf16* __restrict__ qkv, __bf16* __restrict__ Og) {
  __shared__ __align__(16) __bf16 Ps[64 * 72];
  __shared__ __align__(16) __bf16 Vt[32 * 72];
  const int h = blockIdx.x, w = blockIdx.y;   // w group-local; (w&63)==(global&63)
  const int lane = threadIdx.x;
  const int quad = lane >> 4, c = lane & 15;
  const bool whB = (((w & 63) >> 3) == 7), wwB = ((w & 7) == 7);
  const size_t base = (size_t)w * 49 * 1152 + (size_t)h * 32;

  // Q/K fragments straight from global (lane: row t*16+c clamped, 16B at quad*8)
  bf16x8 aq[4], bk[4];
#pragma unroll
  for (int t = 0; t < 4; ++t) {
    int n = t * 16 + c; n = n > 48 ? 48 : n;
    const __bf16* rp = qkv + base + (size_t)n * 1152 + quad * 8;
    aq[t] = *(const bf16x8*)(rp);
    bk[t] = *(const bf16x8*)(rp + 384);
  }

  // V rows -> registers (lane == token m), then transpose-store into Vt
  bf16x8 vr[4];
  if (lane < 49) {
#pragma unroll
    for (int kq = 0; kq < 4; ++kq)
      vr[kq] = *(const bf16x8*)(qkv + base + (size_t)lane * 1152 + 768 + kq * 8);
  }
  {  // zero pad cols 48..63 (col 48 is overwritten by the real stage below)
    uint4 z4 = {0u, 0u, 0u, 0u};
    *(uint4*)(Vt + (lane >> 1) * 72 + 48 + (lane & 1) * 8) = z4;
  }
  if (lane < 49) {
#pragma unroll
    for (int kq = 0; kq < 4; ++kq)
#pragma unroll
      for (int j = 0; j < 8; ++j)
        Vt[(kq * 8 + j) * 72 + lane] = vr[kq][j];
  }

  // S = Q K^T  (padded 64x64)
  f32x4 S4[4][4];
#pragma unroll
  for (int mt = 0; mt < 4; ++mt)
#pragma unroll
    for (int nt = 0; nt < 4; ++nt) S4[mt][nt] = (f32x4){0.f, 0.f, 0.f, 0.f};
#pragma unroll
  for (int mt = 0; mt < 4; ++mt)
#pragma unroll
    for (int nt = 0; nt < 4; ++nt)
      S4[mt][nt] = __builtin_amdgcn_mfma_f32_16x16x32_bf16(aq[mt], bk[nt], S4[mt][nt], 0, 0, 0);

  // mask + softmax in registers; write unnormalized P~ to Ps; keep 1/sum
  bool c28[4], c74[4], cval[4];
#pragma unroll
  for (int nt = 0; nt < 4; ++nt) {
    int col = nt * 16 + c;
    c28[nt]  = col < 28;
    c74[nt]  = (R74 >> col) & 1;
    cval[nt] = col < 49;
  }
  const float scale = 0.17677669529663687f;  // 32^-0.5
  float inv_[4][4];
#pragma unroll
  for (int mt = 0; mt < 4; ++mt) {
#pragma unroll
    for (int r = 0; r < 4; ++r) {
      const int row = mt * 16 + quad * 4 + r;
      const bool r28 = row < 28, r74 = (R74 >> row) & 1;
      float s[4];
#pragma unroll
      for (int nt = 0; nt < 4; ++nt) {
        float v = S4[mt][nt][r] * scale;
        bool bad = (whB && (r28 != c28[nt])) || (wwB && (r74 != c74[nt]));
        v = bad ? v - 100.f : v;
        s[nt] = cval[nt] ? v : -30000.f;   // pad cols: exp -> exactly 0
      }
      float mx = fmaxf(fmaxf(s[0], s[1]), fmaxf(s[2], s[3]));
#pragma unroll
      for (int m_ = 8; m_; m_ >>= 1) mx = fmaxf(mx, __shfl_xor(mx, m_));
      float p[4], sum = 0.f;
#pragma unroll
      for (int nt = 0; nt < 4; ++nt) { p[nt] = __expf(s[nt] - mx); sum += p[nt]; }
#pragma unroll
      for (int m_ = 8; m_; m_ >>= 1) sum += __shfl_xor(sum, m_);
      inv_[mt][r] = 1.f / sum;
#pragma unroll
      for (int nt = 0; nt < 4; ++nt)
        Ps[row * 72 + nt * 16 + c] = (__bf16)p[nt];
    }
  }

  // O = P~ * V  (K padded to 64; pad contributes exact zeros)
  f32x4 Oa[4][2];
#pragma unroll
  for (int mt = 0; mt < 4; ++mt)
#pragma unroll
    for (int nt = 0; nt < 2; ++nt) Oa[mt][nt] = (f32x4){0.f, 0.f, 0.f, 0.f};
#pragma unroll
  for (int ks = 0; ks < 2; ++ks) {
    bf16x8 ap[4], bv[2];
#pragma unroll
    for (int mt = 0; mt < 4; ++mt)
      ap[mt] = *(const bf16x8*)(Ps + (mt * 16 + c) * 72 + ks * 32 + quad * 8);
#pragma unroll
    for (int nt = 0; nt < 2; ++nt)
      bv[nt] = *(const bf16x8*)(Vt + (nt * 16 + c) * 72 + ks * 32 + quad * 8);
#pragma unroll
    for (int mt = 0; mt < 4; ++mt)
#pragma unroll
      for (int nt = 0; nt < 2; ++nt)
        Oa[mt][nt] = __builtin_amdgcn_mfma_f32_16x16x32_bf16(ap[mt], bv[nt], Oa[mt][nt], 0, 0, 0);
  }

  // write O (normalize by deferred 1/sum; rows land on the same lanes as inv_)
#pragma unroll
  for (int mt = 0; mt < 4; ++mt)
#pragma unroll
    for (int r = 0; r < 4; ++r) {
      int n = mt * 16 + quad * 4 + r;
      if (n < 49) {
        float sc_ = inv_[mt][r];
        size_t o = ((size_t)w * 49 + n) * 384 + (size_t)h * 32 + c;
        Og[o]      = (__bf16)(Oa[mt][0][r] * sc_);
        Og[o + 16] = (__bf16)(Oa[mt][1][r] * sc_);
      }
    }
}

// ---------------------------------------------------------------------------
// weight transpose: f32 [K][N] row-major -> bf16 [N][K]
__global__ void transpose_bt(const float* __restrict__ in, bf16* __restrict__ out,
                             int K, int N) {
  int idx = blockIdx.x * 256 + threadIdx.x;
  if (idx < K * N) {
    int k = idx / N, n = idx - k * N;
    out[(size_t)n * K + k] = __float2bfloat16(in[idx]);
  }
}

// ---------------------------------------------------------------------------
extern "C" void kernel_launch(void* const* d_in, const int* in_sizes, int n_in,
                              void* d_out, int out_size, void* d_ws, size_t ws_size,
                              hipStream_t stream) {
  const float* x     = (const float*)d_in[0];
  const float* n1s   = (const float*)d_in[1];
  const float* n1b   = (const float*)d_in[2];
  const float* qkvw  = (const float*)d_in[3];
  const float* qkvb  = (const float*)d_in[4];
  const float* projw = (const float*)d_in[5];
  const float* projb = (const float*)d_in[6];
  const float* n2s   = (const float*)d_in[7];
  const float* n2b   = (const float*)d_in[8];
  const float* fc1w  = (const float*)d_in[9];
  const float* fc1b  = (const float*)d_in[10];
  const float* fc2w  = (const float*)d_in[11];
  const float* fc2b  = (const float*)d_in[12];
  float* out = (float*)d_out;   // doubles as the post-attention residual tensor

  // pick group count from available workspace: need = tok_g*3840 B + 3.4 MB wts
  int ngroup = 16;
  {
    const int cand[4] = {2, 4, 8, 16};
    for (int i = 0; i < 4; ++i) {
      size_t tg = (size_t)TOK_ALL / cand[i];
      if (tg * 3840 + 3538944 <= ws_size) { ngroup = cand[i]; break; }
    }
  }
  const int tok_g = TOK_ALL / ngroup;     // tokens per group
  const int win_g = tok_g / 49;           // windows per group (mult of 64)
  const int mt256 = (tok_g + 255) / 256;  // 256-row M-tiles per group

  // workspace layout (bytes, bf16 buffers)
  const size_t S1 = (size_t)tok_g * 768;    // yg / Og size
  const size_t S3 = (size_t)tok_g * 2304;   // qkvg size
  char* ws = (char*)d_ws;
  bf16* yg   = (bf16*)(ws);                 // LN out (group)
  bf16* Og   = (bf16*)(ws + S1);            // attn out (group)
  bf16* qkvg = (bf16*)(ws + 2 * S1);        // qkv (group)
  bf16* hg   = (bf16*)(ws + S1);            // MLP hidden, reuses Og+qkvg exactly
  char* wb   = ws + 2 * S1 + S3;
  bf16* wT0  = (bf16*)(wb);                             // qkv_w^T  [1152,384]
  bf16* wT1  = (bf16*)(wb + 884736);                    // proj_w^T [384,384]
  bf16* wT2  = (bf16*)(wb + 884736 + 294912);           // fc1_w^T  [1536,384]
  bf16* wT3  = (bf16*)(wb + 884736 + 294912 + 1179648); // fc2_w^T  [384,1536]

  transpose_bt<<<(384 * 1152 + 255) / 256, 256, 0, stream>>>(qkvw, wT0, 384, 1152);
  transpose_bt<<<(384 * 384  + 255) / 256, 256, 0, stream>>>(projw, wT1, 384, 384);
  transpose_bt<<<(384 * 1536 + 255) / 256, 256, 0, stream>>>(fc1w, wT2, 384, 1536);
  transpose_bt<<<(1536 * 384 + 255) / 256, 256, 0, stream>>>(fc2w, wT3, 1536, 384);

  // attention half: out <- x + attn(LN1(x))   (scatter epilogue writes f32 d_out)
  for (int g = 0; g < ngroup; ++g) {
    int roff = g * tok_g;
    ln_kernel<<<tok_g / 4, 256, 0, stream>>>(x, n1s, n1b, yg, 1, roff);
    gemm_bt<0><<<dim3(18, mt256), 256, 0, stream>>>(
        yg, wT0, qkvb, qkvg, nullptr, tok_g, 1152, 384, 0);
    attn_mfma<<<dim3(12, win_g), 64, 0, stream>>>(
        (const __bf16*)qkvg, (__bf16*)Og);
    gemm_bt<1><<<dim3(6, mt256), 256, 0, stream>>>(
        Og, wT1, projb, out, x, tok_g, 384, 384, roff);
  }
  // MLP half: out <- out + fc2(gelu(fc1(LN2(out))))   (in-place f32 resid)
  for (int g = 0; g < ngroup; ++g) {
    long off = (long)g * tok_g * 384;
    ln_kernel<<<tok_g / 4, 256, 0, stream>>>(out + off, n2s, n2b, yg, 0, 0);
    gemm_bt<2><<<dim3(24, mt256), 256, 0, stream>>>(
        yg, wT2, fc1b, hg, nullptr, tok_g, 1536, 384, 0);
    gemm_bt<3><<<dim3(6, mt256), 256, 0, stream>>>(
        hg, wT3, fc2b, out + off, out + off, tok_g, 384, 1536, 0);
  }
}

// Round 4
// 1099.785 us; speedup vs baseline: 1.5386x; 1.5386x over previous
//
#include <hip/hip_runtime.h>
#include <hip/hip_bf16.h>

typedef __hip_bfloat16 bf16;
typedef __bf16 bf16x8 __attribute__((ext_vector_type(8)));
typedef float f32x4 __attribute__((ext_vector_type(4)));

// total tokens: 32 images * 56*56 = 100352; 2048 windows of 49 tokens
constexpr int TOK_ALL = 100352;

// bitmask: bit i set iff (i % 7) < 4   (used for window-region tests, i < 64)
constexpr unsigned long long build_mod7lt4() {
  unsigned long long m = 0;
  for (int i = 0; i < 64; ++i) if (i % 7 < 4) m |= (1ull << i);
  return m;
}
constexpr unsigned long long R74 = build_mod7lt4();

// global window-token row -> (b,h,w) flat index (window reverse + roll(+3,+3))
__device__ __forceinline__ long dst_index(int grow) {
  int w  = grow / 49;
  int n  = grow - w * 49;
  int b  = w >> 6;
  int wi = w & 63;
  int wh = wi >> 3, ww = wi & 7;
  int r  = n / 7,  cl = n - (n / 7) * 7;
  int hh = wh * 7 + r + 3;  if (hh >= 56) hh -= 56;
  int vv = ww * 7 + cl + 3; if (vv >= 56) vv -= 56;
  return ((long)b * 3136 + hh * 56 + vv);
}

// async global->LDS, 16B per lane (global_load_lds_dwordx4)
typedef __attribute__((address_space(1))) void as1_void;
typedef __attribute__((address_space(3))) void as3_void;
__device__ __forceinline__ void gload16(const void* g, void* l) {
  __builtin_amdgcn_global_load_lds((as1_void*)g, (as3_void*)l, 16, 0, 0);
}

// ---------------------------------------------------------------------------
// TN GEMM: C[M,N] = A[M,K] (row-major bf16) * Bt[N,K]^T (bf16), fused epilogues.
// 128x128 tile, BK=64, double-buffered LDS with prefetch-before-compute
// (T3-minimum: one vmcnt-draining barrier per K-step). LDS kept LINEAR for
// global_load_lds; bank conflicts killed by the T2 both-sides involution:
// global source col pre-XORed by ((lane&7)^(lane>>3))<<4, ds_read col XORed
// by (c&7)<<4 (16-way -> 2-way, free). T1 bijective XCD-chunked block swizzle
// keeps same-A-row blocks on one XCD's L2.
// EPI: 0 = +bias -> bf16, 1 = +bias + scatter + f32 resid -> f32,
//      2 = +bias + tanh-GELU -> bf16, 3 = +bias + f32 resid -> f32 (in-place ok)
template <int EPI>
__global__ __launch_bounds__(256) void gemm_bt(
    const bf16* __restrict__ A, const bf16* __restrict__ Bt,
    const float* __restrict__ bias, void* __restrict__ Cout_,
    const float* __restrict__ resid, int M, int N, int K, int rowoff) {
  __shared__ __align__(16) char As[2][128 * 128];  // 2 x 16KB (128 rows x 128B)
  __shared__ __align__(16) char Bs[2][128 * 128];

  const int tid  = threadIdx.x;
  const int wv   = tid >> 6;
  const int lane = tid & 63;
  const int quad = lane >> 4;
  const int c    = lane & 15;

  // T1: bijective XCD-chunked swizzle (m204). orig%8 ~ XCD; each XCD gets a
  // contiguous flat range -> consecutive n-blocks of one m-row share its L2.
  const int nx  = gridDim.x;
  const int nwg = nx * gridDim.y;
  {
  }
  int orig = blockIdx.y * nx + blockIdx.x;
  int q8 = nwg >> 3, r8 = nwg & 7, xcd = orig & 7, sub = orig >> 3;
  int flat = (xcd < r8 ? xcd * (q8 + 1) : r8 * (q8 + 1) + (xcd - r8) * q8) + sub;
  const int n0 = (flat % nx) * 128;
  const int m0 = (flat / nx) * 128;

  const int wm   = wv >> 1, wn = wv & 1;
  const int rA0  = wm * 64 + c;
  const int rB0  = wn * 64 + c;
  const int rsw  = (c & 7) << 4;          // read-side XOR (bits 4..6)

  const size_t rowb = (size_t)K * 2;
  const char*  Ab = (const char*)A  + (size_t)m0 * rowb;
  const char*  Bb = (const char*)Bt + (size_t)n0 * rowb;

  // staging geometry: pass p covers rows [p*32, p*32+32); wave wv owns 8 rows;
  // lane covers 16B. LDS byte p*4096 + wv*1024 + lane*16 == row*128 + col.
  // T2: global source col pre-XORed so LDS holds the swizzled layout.
  const int srow = wv * 8 + (lane >> 3);
  const int scol = (((lane & 7) ^ (lane >> 3)) & 7) << 4;

  f32x4 acc[4][4];
#pragma unroll
  for (int i = 0; i < 4; ++i)
#pragma unroll
    for (int j = 0; j < 4; ++j) acc[i][j] = (f32x4){0.f, 0.f, 0.f, 0.f};

  const int nsteps = K >> 6;

  // prologue: stage step 0 into buffer 0
  {
    const size_t kb0 = 0;
#pragma unroll
    for (int p = 0; p < 4; ++p) {
      const size_t rb = (size_t)(p * 32 + srow) * rowb + kb0 + scol;
      gload16(Ab + rb, &As[0][p * 4096 + wv * 1024]);
      gload16(Bb + rb, &Bs[0][p * 4096 + wv * 1024]);
    }
  }
  __syncthreads();

  for (int t = 0; t < nsteps; ++t) {
    const int cur = t & 1;
    if (t + 1 < nsteps) {   // prefetch next K-step into the other buffer
      const size_t kb = (size_t)(t + 1) * 128;   // (t+1)*64 bf16 = 128B
#pragma unroll
      for (int p = 0; p < 4; ++p) {
        const size_t rb = (size_t)(p * 32 + srow) * rowb + kb + scol;
        gload16(Ab + rb, &As[cur ^ 1][p * 4096 + wv * 1024]);
        gload16(Bb + rb, &Bs[cur ^ 1][p * 4096 + wv * 1024]);
      }
    }
#pragma unroll
    for (int kk = 0; kk < 2; ++kk) {
      bf16x8 af[4], bfr[4];
      const int col = (kk * 64 + quad * 16) ^ rsw;
#pragma unroll
      for (int tt = 0; tt < 4; ++tt) {
        af[tt]  = *(const bf16x8*)(&As[cur][(rA0 + tt * 16) * 128 + col]);
        bfr[tt] = *(const bf16x8*)(&Bs[cur][(rB0 + tt * 16) * 128 + col]);
      }
#pragma unroll
      for (int mt = 0; mt < 4; ++mt)
#pragma unroll
        for (int nt = 0; nt < 4; ++nt)
          acc[mt][nt] = __builtin_amdgcn_mfma_f32_16x16x32_bf16(af[mt], bfr[nt], acc[mt][nt], 0, 0, 0);
    }
    __syncthreads();   // drains vmcnt(0): next buffer staged + all done with cur
  }

  // epilogue  (C/D layout: col = lane&15, row = quad*4 + reg)
  bf16*  CoutB = (bf16*)Cout_;
  float* CoutF = (float*)Cout_;
  float bcol[4];
#pragma unroll
  for (int nt = 0; nt < 4; ++nt)
    bcol[nt] = bias[n0 + wn * 64 + nt * 16 + c];

#pragma unroll
  for (int mt = 0; mt < 4; ++mt) {
#pragma unroll
    for (int r = 0; r < 4; ++r) {
      int grow = m0 + wm * 64 + mt * 16 + quad * 4 + r;
      long dst_row = 0;
      if constexpr (EPI == 1) dst_row = dst_index(rowoff + grow);
#pragma unroll
      for (int nt = 0; nt < 4; ++nt) {
        int col = n0 + wn * 64 + nt * 16 + c;
        float v = acc[mt][nt][r] + bcol[nt];
        if constexpr (EPI == 0) {
          CoutB[(size_t)grow * N + col] = __float2bfloat16(v);
        } else if constexpr (EPI == 1) {
          size_t dst = (size_t)dst_row * 384 + col;
          CoutF[dst] = v + resid[dst];
        } else if constexpr (EPI == 2) {
          float u = 0.7978845608f * (v + 0.044715f * v * v * v);
          float t2 = __expf(2.f * u);
          float g = v * (1.f - 1.f / (t2 + 1.f));   // 0.5*v*(1+tanh(u))
          CoutB[(size_t)grow * N + col] = __float2bfloat16(g);
        } else {
          size_t dst = (size_t)grow * N + col;
          CoutF[dst] = v + resid[dst];
        }
      }
    }
  }
}

// ---------------------------------------------------------------------------
// LayerNorm, one wave per token; f32 in -> bf16 out.
// gather=1: LN1 + roll(-3,-3) + window partition (rows in window order)
__global__ __launch_bounds__(256) void ln_kernel(
    const float* __restrict__ x, const float* __restrict__ sc,
    const float* __restrict__ bi, bf16* __restrict__ y, int gather, int goff) {
  int tok  = blockIdx.x * 4 + (threadIdx.x >> 6);
  int lane = threadIdx.x & 63;
  size_t src;
  if (gather) {
    int tg = goff + tok;
    int w  = tg / 49, n = tg - (tg / 49) * 49;
    int b  = w >> 6, wi = w & 63;
    int wh = wi >> 3, ww = wi & 7;
    int r  = n / 7, cl = n - (n / 7) * 7;
    int hh = wh * 7 + r + 3;  if (hh >= 56) hh -= 56;
    int vv = ww * 7 + cl + 3; if (vv >= 56) vv -= 56;
    src = ((size_t)b * 3136 + hh * 56 + vv) * 384;
  } else {
    src = (size_t)tok * 384;
  }
  float v[6], s = 0.f, sq = 0.f;
#pragma unroll
  for (int j = 0; j < 6; ++j) {
    v[j] = x[src + lane + j * 64];
    s += v[j]; sq += v[j] * v[j];
  }
#pragma unroll
  for (int m = 32; m; m >>= 1) { s += __shfl_xor(s, m); sq += __shfl_xor(sq, m); }
  float mu  = s * (1.f / 384.f);
  float var = sq * (1.f / 384.f) - mu * mu;
  float rs  = rsqrtf(var + 1e-6f);
#pragma unroll
  for (int j = 0; j < 6; ++j) {
    int c = lane + j * 64;
    y[(size_t)tok * 384 + c] = __float2bfloat16((v[j] - mu) * rs * sc[c] + bi[c]);
  }
}

// ---------------------------------------------------------------------------
// MFMA attention: one wave (64-thread block) per (window, head). N=49, Dh=32.
__global__ __launch_bounds__(64) void attn_mfma(
    const __bf16* __restrict__ qkv, __bf16* __restrict__ Og) {
  __shared__ __align__(16) __bf16 Ps[64 * 72];
  __shared__ __align__(16) __bf16 Vt[32 * 72];
  const int h = blockIdx.x, w = blockIdx.y;   // w group-local; (w&63)==(global&63)
  const int lane = threadIdx.x;
  const int quad = lane >> 4, c = lane & 15;
  const bool whB = (((w & 63) >> 3) == 7), wwB = ((w & 7) == 7);
  const size_t base = (size_t)w * 49 * 1152 + (size_t)h * 32;

  // Q/K fragments straight from global (lane: row t*16+c clamped, 16B at quad*8)
  bf16x8 aq[4], bk[4];
#pragma unroll
  for (int t = 0; t < 4; ++t) {
    int n = t * 16 + c; n = n > 48 ? 48 : n;
    const __bf16* rp = qkv + base + (size_t)n * 1152 + quad * 8;
    aq[t] = *(const bf16x8*)(rp);
    bk[t] = *(const bf16x8*)(rp + 384);
  }

  // V rows -> registers (lane == token m), then transpose-store into Vt
  bf16x8 vr[4];
  if (lane < 49) {
#pragma unroll
    for (int kq = 0; kq < 4; ++kq)
      vr[kq] = *(const bf16x8*)(qkv + base + (size_t)lane * 1152 + 768 + kq * 8);
  }
  {  // zero pad cols 48..63 (col 48 is overwritten by the real stage below)
    uint4 z4 = {0u, 0u, 0u, 0u};
    *(uint4*)(Vt + (lane >> 1) * 72 + 48 + (lane & 1) * 8) = z4;
  }
  if (lane < 49) {
#pragma unroll
    for (int kq = 0; kq < 4; ++kq)
#pragma unroll
      for (int j = 0; j < 8; ++j)
        Vt[(kq * 8 + j) * 72 + lane] = vr[kq][j];
  }

  // S = Q K^T  (padded 64x64)
  f32x4 S4[4][4];
#pragma unroll
  for (int mt = 0; mt < 4; ++mt)
#pragma unroll
    for (int nt = 0; nt < 4; ++nt) S4[mt][nt] = (f32x4){0.f, 0.f, 0.f, 0.f};
#pragma unroll
  for (int mt = 0; mt < 4; ++mt)
#pragma unroll
    for (int nt = 0; nt < 4; ++nt)
      S4[mt][nt] = __builtin_amdgcn_mfma_f32_16x16x32_bf16(aq[mt], bk[nt], S4[mt][nt], 0, 0, 0);

  // mask + softmax in registers; write unnormalized P~ to Ps; keep 1/sum
  bool c28[4], c74[4], cval[4];
#pragma unroll
  for (int nt = 0; nt < 4; ++nt) {
    int col = nt * 16 + c;
    c28[nt]  = col < 28;
    c74[nt]  = (R74 >> col) & 1;
    cval[nt] = col < 49;
  }
  const float scale = 0.17677669529663687f;  // 32^-0.5
  float inv_[4][4];
#pragma unroll
  for (int mt = 0; mt < 4; ++mt) {
#pragma unroll
    for (int r = 0; r < 4; ++r) {
      const int row = mt * 16 + quad * 4 + r;
      const bool r28 = row < 28, r74 = (R74 >> row) & 1;
      float s[4];
#pragma unroll
      for (int nt = 0; nt < 4; ++nt) {
        float v = S4[mt][nt][r] * scale;
        bool bad = (whB && (r28 != c28[nt])) || (wwB && (r74 != c74[nt]));
        v = bad ? v - 100.f : v;
        s[nt] = cval[nt] ? v : -30000.f;   // pad cols: exp -> exactly 0
      }
      float mx = fmaxf(fmaxf(s[0], s[1]), fmaxf(s[2], s[3]));
#pragma unroll
      for (int m_ = 8; m_; m_ >>= 1) mx = fmaxf(mx, __shfl_xor(mx, m_));
      float p[4], sum = 0.f;
#pragma unroll
      for (int nt = 0; nt < 4; ++nt) { p[nt] = __expf(s[nt] - mx); sum += p[nt]; }
#pragma unroll
      for (int m_ = 8; m_; m_ >>= 1) sum += __shfl_xor(sum, m_);
      inv_[mt][r] = 1.f / sum;
#pragma unroll
      for (int nt = 0; nt < 4; ++nt)
        Ps[row * 72 + nt * 16 + c] = (__bf16)p[nt];
    }
  }

  // O = P~ * V  (K padded to 64; pad contributes exact zeros)
  f32x4 Oa[4][2];
#pragma unroll
  for (int mt = 0; mt < 4; ++mt)
#pragma unroll
    for (int nt = 0; nt < 2; ++nt) Oa[mt][nt] = (f32x4){0.f, 0.f, 0.f, 0.f};
#pragma unroll
  for (int ks = 0; ks < 2; ++ks) {
    bf16x8 ap[4], bv[2];
#pragma unroll
    for (int mt = 0; mt < 4; ++mt)
      ap[mt] = *(const bf16x8*)(Ps + (mt * 16 + c) * 72 + ks * 32 + quad * 8);
#pragma unroll
    for (int nt = 0; nt < 2; ++nt)
      bv[nt] = *(const bf16x8*)(Vt + (nt * 16 + c) * 72 + ks * 32 + quad * 8);
#pragma unroll
    for (int mt = 0; mt < 4; ++mt)
#pragma unroll
      for (int nt = 0; nt < 2; ++nt)
        Oa[mt][nt] = __builtin_amdgcn_mfma_f32_16x16x32_bf16(ap[mt], bv[nt], Oa[mt][nt], 0, 0, 0);
  }

  // write O (normalize by deferred 1/sum; rows land on the same lanes as inv_)
#pragma unroll
  for (int mt = 0; mt < 4; ++mt)
#pragma unroll
    for (int r = 0; r < 4; ++r) {
      int n = mt * 16 + quad * 4 + r;
      if (n < 49) {
        float sc_ = inv_[mt][r];
        size_t o = ((size_t)w * 49 + n) * 384 + (size_t)h * 32 + c;
        Og[o]      = (__bf16)(Oa[mt][0][r] * sc_);
        Og[o + 16] = (__bf16)(Oa[mt][1][r] * sc_);
      }
    }
}

// ---------------------------------------------------------------------------
// weight transpose: f32 [K][N] row-major -> bf16 [N][K]
__global__ void transpose_bt(const float* __restrict__ in, bf16* __restrict__ out,
                             int K, int N) {
  int idx = blockIdx.x * 256 + threadIdx.x;
  if (idx < K * N) {
    int k = idx / N, n = idx - k * N;
    out[(size_t)n * K + k] = __float2bfloat16(in[idx]);
  }
}

// ---------------------------------------------------------------------------
extern "C" void kernel_launch(void* const* d_in, const int* in_sizes, int n_in,
                              void* d_out, int out_size, void* d_ws, size_t ws_size,
                              hipStream_t stream) {
  const float* x     = (const float*)d_in[0];
  const float* n1s   = (const float*)d_in[1];
  const float* n1b   = (const float*)d_in[2];
  const float* qkvw  = (const float*)d_in[3];
  const float* qkvb  = (const float*)d_in[4];
  const float* projw = (const float*)d_in[5];
  const float* projb = (const float*)d_in[6];
  const float* n2s   = (const float*)d_in[7];
  const float* n2b   = (const float*)d_in[8];
  const float* fc1w  = (const float*)d_in[9];
  const float* fc1b  = (const float*)d_in[10];
  const float* fc2w  = (const float*)d_in[11];
  const float* fc2b  = (const float*)d_in[12];
  float* out = (float*)d_out;   // doubles as the post-attention residual tensor

  // pick group count from available workspace: need = tok_g*3840 B + 3.4 MB wts
  int ngroup = 16;
  {
    const int cand[4] = {2, 4, 8, 16};
    for (int i = 0; i < 4; ++i) {
      size_t tg = (size_t)TOK_ALL / cand[i];
      if (tg * 3840 + 3538944 <= ws_size) { ngroup = cand[i]; break; }
    }
  }
  const int tok_g = TOK_ALL / ngroup;     // tokens per group
  const int win_g = tok_g / 49;           // windows per group (mult of 64)

  // workspace layout (bytes, bf16 buffers)
  const size_t S1 = (size_t)tok_g * 768;    // yg / Og size
  const size_t S3 = (size_t)tok_g * 2304;   // qkvg size
  char* ws = (char*)d_ws;
  bf16* yg   = (bf16*)(ws);                 // LN out (group)
  bf16* Og   = (bf16*)(ws + S1);            // attn out (group)
  bf16* qkvg = (bf16*)(ws + 2 * S1);        // qkv (group)
  bf16* hg   = (bf16*)(ws + S1);            // MLP hidden, reuses Og+qkvg exactly
  char* wb   = ws + 2 * S1 + S3;
  bf16* wT0  = (bf16*)(wb);                             // qkv_w^T  [1152,384]
  bf16* wT1  = (bf16*)(wb + 884736);                    // proj_w^T [384,384]
  bf16* wT2  = (bf16*)(wb + 884736 + 294912);           // fc1_w^T  [1536,384]
  bf16* wT3  = (bf16*)(wb + 884736 + 294912 + 1179648); // fc2_w^T  [384,1536]

  transpose_bt<<<(384 * 1152 + 255) / 256, 256, 0, stream>>>(qkvw, wT0, 384, 1152);
  transpose_bt<<<(384 * 384  + 255) / 256, 256, 0, stream>>>(projw, wT1, 384, 384);
  transpose_bt<<<(384 * 1536 + 255) / 256, 256, 0, stream>>>(fc1w, wT2, 384, 1536);
  transpose_bt<<<(1536 * 384 + 255) / 256, 256, 0, stream>>>(fc2w, wT3, 1536, 384);

  // attention half: out <- x + attn(LN1(x))   (scatter epilogue writes f32 d_out)
  for (int g = 0; g < ngroup; ++g) {
    int roff = g * tok_g;
    ln_kernel<<<tok_g / 4, 256, 0, stream>>>(x, n1s, n1b, yg, 1, roff);
    gemm_bt<0><<<dim3(9, tok_g / 128), 256, 0, stream>>>(
        yg, wT0, qkvb, qkvg, nullptr, tok_g, 1152, 384, 0);
    attn_mfma<<<dim3(12, win_g), 64, 0, stream>>>(
        (const __bf16*)qkvg, (__bf16*)Og);
    gemm_bt<1><<<dim3(3, tok_g / 128), 256, 0, stream>>>(
        Og, wT1, projb, out, x, tok_g, 384, 384, roff);
  }
  // MLP half: out <- out + fc2(gelu(fc1(LN2(out))))   (in-place f32 resid)
  for (int g = 0; g < ngroup; ++g) {
    long off = (long)g * tok_g * 384;
    ln_kernel<<<tok_g / 4, 256, 0, stream>>>(out + off, n2s, n2b, yg, 0, 0);
    gemm_bt<2><<<dim3(12, tok_g / 128), 256, 0, stream>>>(
        yg, wT2, fc1b, hg, nullptr, tok_g, 1536, 384, 0);
    gemm_bt<3><<<dim3(3, tok_g / 128), 256, 0, stream>>>(
        hg, wT3, fc2b, out + off, out + off, tok_g, 384, 1536, 0);
  }
}